// Round 1
// baseline (1095.437 us; speedup 1.0000x reference)
//
#include <hip/hip_runtime.h>
#include <cmath>

// Problem constants
#define BSZ   2048
#define TSTEP 64
#define HDIM  1024
#define RTOT  (BSZ * TSTEP)   // 131072 rows
#define MEMN  32

// ---------------------------------------------------------------------------
// LDS-only barrier: orders LDS traffic across the block WITHOUT the
// __syncthreads() vmcnt(0) drain, so in-flight global prefetch loads stay in
// flight across the barrier (T4: never drain vmcnt in the main loop).
// ---------------------------------------------------------------------------
__device__ __forceinline__ void lds_barrier() {
    asm volatile("s_waitcnt lgkmcnt(0)\n\ts_barrier" ::: "memory");
}

// ---------------------------------------------------------------------------
// Kernel 1: projection GEMM  (RTOT x HDIM) @ (HDIM x 97) -> G, Q, FK, FV
// Columns: 0..31 = query, 32..63 = fk, 64..95 = fv, 96 = gate (sigmoid).
// fp32 vector GEMM. BM=256, BN=128 (pad >=97 with zeros), BK=32.
// NEW vs 1102.6µs version: register double-buffer prefetch of the next
// k0-tile (T14) + lgkm-only barriers (T4) so global staging latency hides
// under the 32-step FMA phase instead of being exposed per tile.
// ---------------------------------------------------------------------------
constexpr int BM = 256, BN = 128, BK = 32;

__global__ __launch_bounds__(256, 2) void proj_kernel(
    const float* __restrict__ h,
    const float* __restrict__ Wg,  const float* __restrict__ bg,
    const float* __restrict__ Wq,  const float* __restrict__ bq,
    const float* __restrict__ Wfk, const float* __restrict__ bfk,
    const float* __restrict__ Wfv, const float* __restrict__ bfv,
    float* __restrict__ G, float* __restrict__ Qo,
    float* __restrict__ FKo, float* __restrict__ FVo)
{
    __shared__ __align__(16) float Xs[BK][BM + 4];  // Xs[k][row] (stride 260)
    __shared__ __align__(16) float Ws[BK][BN + 4];  // Ws[k][col] (stride 132)

    const int tid  = threadIdx.x;
    const int tx   = tid & 15;    // 0..15 col groups
    const int ty   = tid >> 4;    // 0..15 row groups
    const int row0 = blockIdx.x * BM;

    float acc[16][8] = {};

    // --- invariant staging descriptors ---
    const float* xsrc = &h[(size_t)(row0 + tid) * HDIM];
    const float* wrow[4];
    int wnn[4], wq4[4];
#pragma unroll
    for (int it = 0; it < 4; ++it) {
        const int task = tid + it * 256;
        const int nn   = task & 127;
        const int kq   = task >> 7;      // 0..7
        const float* src = nullptr;
        if (nn < 32)       src = Wq  + (size_t)nn * HDIM;
        else if (nn < 64)  src = Wfk + (size_t)(nn - 32) * HDIM;
        else if (nn < 96)  src = Wfv + (size_t)(nn - 64) * HDIM;
        else if (nn == 96) src = Wg;
        wrow[it] = src; wnn[it] = nn; wq4[it] = kq;
    }

    // --- prologue: load tile k0=0 into registers ---
    float4 xv[8], wv[4];
#pragma unroll
    for (int q = 0; q < 8; ++q)
        xv[q] = *reinterpret_cast<const float4*>(xsrc + q * 4);
#pragma unroll
    for (int it = 0; it < 4; ++it)
        wv[it] = wrow[it]
            ? *reinterpret_cast<const float4*>(wrow[it] + wq4[it] * 4)
            : make_float4(0.f, 0.f, 0.f, 0.f);

    for (int k0 = 0; k0 < HDIM; k0 += BK) {
        lds_barrier();   // all waves done READING previous tile (lgkm only)

        // --- write staged registers to LDS (waits on own loads via vmcnt dep) ---
        // ds_write bank = (quad*4 + tid) % 32 -> 2-way across 64 lanes (free).
#pragma unroll
        for (int q = 0; q < 8; ++q) {
            Xs[q * 4 + 0][tid] = xv[q].x;
            Xs[q * 4 + 1][tid] = xv[q].y;
            Xs[q * 4 + 2][tid] = xv[q].z;
            Xs[q * 4 + 3][tid] = xv[q].w;
        }
#pragma unroll
        for (int it = 0; it < 4; ++it) {
            Ws[wq4[it] * 4 + 0][wnn[it]] = wv[it].x;
            Ws[wq4[it] * 4 + 1][wnn[it]] = wv[it].y;
            Ws[wq4[it] * 4 + 2][wnn[it]] = wv[it].z;
            Ws[wq4[it] * 4 + 3][wnn[it]] = wv[it].w;
        }

        // --- issue prefetch for next tile; stays in flight through compute ---
        const int k0n = (k0 + BK < HDIM) ? (k0 + BK) : k0;  // tail: reload (unused)
#pragma unroll
        for (int q = 0; q < 8; ++q)
            xv[q] = *reinterpret_cast<const float4*>(xsrc + k0n + q * 4);
#pragma unroll
        for (int it = 0; it < 4; ++it)
            wv[it] = wrow[it]
                ? *reinterpret_cast<const float4*>(wrow[it] + k0n + wq4[it] * 4)
                : make_float4(0.f, 0.f, 0.f, 0.f);

        lds_barrier();   // tile visible; prefetch NOT drained (no vmcnt wait)

        for (int k = 0; k < BK; ++k) {
            float av[16], bv[8];
#pragma unroll
            for (int g = 0; g < 4; ++g) {
                const float4 a = *reinterpret_cast<const float4*>(&Xs[k][g * 64 + ty * 4]);
                av[g * 4 + 0] = a.x; av[g * 4 + 1] = a.y;
                av[g * 4 + 2] = a.z; av[g * 4 + 3] = a.w;
            }
            const float4 b0 = *reinterpret_cast<const float4*>(&Ws[k][tx * 4]);
            const float4 b1 = *reinterpret_cast<const float4*>(&Ws[k][64 + tx * 4]);
            bv[0] = b0.x; bv[1] = b0.y; bv[2] = b0.z; bv[3] = b0.w;
            bv[4] = b1.x; bv[5] = b1.y; bv[6] = b1.z; bv[7] = b1.w;
#pragma unroll
            for (int i = 0; i < 16; ++i)
#pragma unroll
                for (int j = 0; j < 8; ++j)
                    acc[i][j] = fmaf(av[i], bv[j], acc[i][j]);
        }
    }

    // --- epilogue: row i -> (i>>2)*64 + ty*4 + (i&3) ---
#pragma unroll
    for (int i = 0; i < 16; ++i) {
        const int rl = (i >> 2) * 64 + ty * 4 + (i & 3);
        const size_t r = (size_t)row0 + rl;
#pragma unroll
        for (int j = 0; j < 8; ++j) {
            const int c = (j < 4) ? (tx * 4 + j) : (64 + tx * 4 + (j - 4));
            const float v = acc[i][j];
            if (c < 32)        Qo [r * 32 + c]        = v + bq[c];
            else if (c < 64)   FKo[r * 32 + (c - 32)] = v + bfk[c - 32];
            else if (c < 96)   FVo[r * 32 + (c - 64)] = v + bfv[c - 64];
            else if (c == 96) {
                const float x = v + bg[0];
                G[r] = 1.f / (1.f + expf(-x));   // p_reuse
            }
        }
    }
}

// ---------------------------------------------------------------------------
// Kernel 2: recurrence. One 32-lane half-wave per batch element.
// Block = 128 threads = 4 batch elements. Grid = 2048/4 = 512.
//
// NEW vs 1102.6µs version:
//  * ZERO barriers. Every LDS array is indexed by el, and each el group is
//    32 lanes inside ONE wave -> all cross-lane traffic is wave-internal.
//    CDNA waves are lockstep; compiler same-array aliasing preserves the
//    ds_write -> ds_read order with counted lgkmcnt (no full drains, and
//    iterations can overlap).
//  * V stored transposed: Vt[el][v][slot] = V[slot][v]. retrv becomes 8x
//    ds_read_b128 per lane (contiguous over slot) instead of 32x b32; the
//    eviction write stays one b32/lane (bank (m+ei)%32, conflict-free).
//  * argmin(Tf)/mask-sum butterflies (register-only inputs) hoisted above
//    the LDS phase so their swizzle chains overlap the global prefetch.
// ---------------------------------------------------------------------------
__global__ __launch_bounds__(128) void recur_kernel(
    const float* __restrict__ G,  const float* __restrict__ Qp,
    const float* __restrict__ FKp, const float* __restrict__ FVp,
    float* __restrict__ out)
{
    __shared__ float Ks[4][MEMN][33];   // Ks[el][slot][key]
    __shared__ float Vt[4][MEMN][33];   // Vt[el][val][slot]  (transposed V)
    __shared__ float qs[4][MEMN];
    __shared__ float attn_s[4][MEMN];

    const int tid = threadIdx.x;
    const int el  = tid >> 5;          // 0..3 local batch element
    const int m   = tid & 31;          // slot / lane index
    const size_t b = (size_t)blockIdx.x * 4 + el;

#pragma unroll
    for (int k = 0; k < MEMN; ++k) { Ks[el][m][k] = 0.f; Vt[el][m][k] = 0.f; }
    float Tf  = 0.f;
    float msk = 0.f;
    // no barrier needed: each el group touches only its own arrays (one wave)

    const float scale = 0.17677669529663687f;  // 1/sqrt(32)
    float* es_out = out;
    float* ps_out = out + (size_t)RTOT * 32;

    size_t r = b * TSTEP;
    float q  = Qp [r * 32 + m];
    float fk = FKp[r * 32 + m];
    float fv = FVp[r * 32 + m];
    float p  = G[r];

    for (int t = 0; t < TSTEP; ++t) {
        // prefetch next step (clamped at the tail; re-load is harmless)
        const size_t rn = r + ((t < TSTEP - 1) ? 1 : 0);
        const float qn  = Qp [rn * 32 + m];
        const float fkn = FKp[rn * 32 + m];
        const float fvn = FVp[rn * 32 + m];
        const float pn  = G[rn];

        // ---- register-only reductions first (overlap with prefetch) ----
        // mask sum (empty_row)
        float smk = msk;
#pragma unroll
        for (int d = 16; d >= 1; d >>= 1) smk += __shfl_xor(smk, d);
        // argmin(Tf + mask*0.001), first-index tie-break (jnp.argmin)
        float evv = Tf + msk * 0.001f; int ei = m;
#pragma unroll
        for (int d = 16; d >= 1; d >>= 1) {
            const float ov = __shfl_xor(evv, d);
            const int   oi = __shfl_xor(ei, d);
            if (ov < evv || (ov == evv && oi < ei)) { evv = ov; ei = oi; }
        }

        // ---- logits ----
        qs[el][m] = q;
        float accv = 0.f;
#pragma unroll
        for (int k = 0; k < MEMN; ++k) accv = fmaf(Ks[el][m][k], qs[el][k], accv);
        const float lg = accv * scale + (1.f - msk) * (-1e9f);

        // softmax over 32 lanes
        float mx = lg;
#pragma unroll
        for (int d = 16; d >= 1; d >>= 1) mx = fmaxf(mx, __shfl_xor(mx, d));
        const float pe = expf(lg - mx);
        float ssum = pe;
#pragma unroll
        for (int d = 16; d >= 1; d >>= 1) ssum += __shfl_xor(ssum, d);
        const float attn = pe / ssum;
        attn_s[el][m] = attn;

        // argmax(attn), first-index tie-break (jnp.argmax semantics)
        float av = attn; int ai = m;
#pragma unroll
        for (int d = 16; d >= 1; d >>= 1) {
            const float ov = __shfl_xor(av, d);
            const int   oi = __shfl_xor(ai, d);
            if (ov > av || (ov == av && oi < ai)) { av = ov; ai = oi; }
        }

        // ---- retrv[m] = sum_k attn[k] * V[k][m] = sum_k attn[k]*Vt[m][k] ----
        float rv = 0.f;
#pragma unroll
        for (int k = 0; k < MEMN; ++k) rv = fmaf(attn_s[el][k], Vt[el][m][k], rv);

        const float empty = (smk == 0.f) ? 1.f : 0.f;
        const float warm  = (t < 4) ? 1.f : 0.f;
        const float gate  = p * (1.f - empty) * (1.f - warm);
        const float e_val = gate * rv + (1.f - gate) * fv;

        es_out[r * 32 + m] = e_val;
        if (m == 0) ps_out[r] = p;

        const bool wr = (gate < 0.5f) || (warm > 0.f);

        // ---- state update (wave-internal; ordered by lgkm deps next iter) ----
        if (wr) { Ks[el][ei][m] = fk; Vt[el][m][ei] = fv; }

        const float x = Tf * 0.85f;
        const bool bump = wr ? (m == ei) : (m == ai);
        Tf = bump ? (x + (1.f - x)) : x;
        if (wr && m == ei) msk = 1.f;

        q = qn; fk = fkn; fv = fvn; p = pn; r = rn;
    }
}

// ---------------------------------------------------------------------------
extern "C" void kernel_launch(void* const* d_in, const int* in_sizes, int n_in,
                              void* d_out, int out_size, void* d_ws, size_t ws_size,
                              hipStream_t stream) {
    const float* h   = (const float*)d_in[0];
    const float* Wg  = (const float*)d_in[1];
    const float* bg  = (const float*)d_in[2];
    const float* Wq  = (const float*)d_in[3];
    const float* bq  = (const float*)d_in[4];
    const float* Wfk = (const float*)d_in[5];
    const float* bfk = (const float*)d_in[6];
    const float* Wfv = (const float*)d_in[7];
    const float* bfv = (const float*)d_in[8];

    // workspace: G[RTOT], Q[RTOT*32], FK[RTOT*32], FV[RTOT*32]
    float* G   = (float*)d_ws;
    float* Qp  = G + RTOT;
    float* FKp = Qp + (size_t)RTOT * 32;
    float* FVp = FKp + (size_t)RTOT * 32;

    proj_kernel<<<RTOT / BM, 256, 0, stream>>>(h, Wg, bg, Wq, bq, Wfk, bfk,
                                               Wfv, bfv, G, Qp, FKp, FVp);
    recur_kernel<<<BSZ / 4, 128, 0, stream>>>(G, Qp, FKp, FVp, (float*)d_out);
}

// Round 2
// 1054.316 us; speedup vs baseline: 1.0390x; 1.0390x over previous
//
#include <hip/hip_runtime.h>
#include <cmath>

// Problem constants
#define BSZ   2048
#define TSTEP 64
#define HDIM  1024
#define RTOT  (BSZ * TSTEP)   // 131072 rows
#define MEMN  32

// ---------------------------------------------------------------------------
// LDS-only barrier: orders LDS traffic across the block WITHOUT the
// __syncthreads() vmcnt(0) drain (proj staging prefetch stays in flight).
// ---------------------------------------------------------------------------
__device__ __forceinline__ void lds_barrier() {
    asm volatile("s_waitcnt lgkmcnt(0)\n\ts_barrier" ::: "memory");
}

// ---------------------------------------------------------------------------
// Kernel 1: projection GEMM  (RTOT x HDIM) @ (HDIM x 97) -> G, Q, FK, FV
// fp32 vector GEMM. BM=256, BN=128 (pad >=97 with zeros), BK=32.
// NEW this round: #pragma unroll 4 on the k-loop. With 2 waves/SIMD the
// un-unrolled loop exposed the ~120cy ds_read latency every k-step
// (VALUBusy 58%); a 4-deep window lets k+1..k+3 reads issue under k's
// 256cy FMA block.
// ---------------------------------------------------------------------------
constexpr int BM = 256, BN = 128, BK = 32;

__global__ __launch_bounds__(256, 2) void proj_kernel(
    const float* __restrict__ h,
    const float* __restrict__ Wg,  const float* __restrict__ bg,
    const float* __restrict__ Wq,  const float* __restrict__ bq,
    const float* __restrict__ Wfk, const float* __restrict__ bfk,
    const float* __restrict__ Wfv, const float* __restrict__ bfv,
    float* __restrict__ G, float* __restrict__ Qo,
    float* __restrict__ FKo, float* __restrict__ FVo)
{
    __shared__ __align__(16) float Xs[BK][BM + 4];  // Xs[k][row] (stride 260)
    __shared__ __align__(16) float Ws[BK][BN + 4];  // Ws[k][col] (stride 132)

    const int tid  = threadIdx.x;
    const int tx   = tid & 15;    // 0..15 col groups
    const int ty   = tid >> 4;    // 0..15 row groups
    const int row0 = blockIdx.x * BM;

    float acc[16][8] = {};

    // --- invariant staging descriptors ---
    const float* xsrc = &h[(size_t)(row0 + tid) * HDIM];
    const float* wrow[4];
    int wnn[4], wq4[4];
#pragma unroll
    for (int it = 0; it < 4; ++it) {
        const int task = tid + it * 256;
        const int nn   = task & 127;
        const int kq   = task >> 7;      // 0..7
        const float* src = nullptr;
        if (nn < 32)       src = Wq  + (size_t)nn * HDIM;
        else if (nn < 64)  src = Wfk + (size_t)(nn - 32) * HDIM;
        else if (nn < 96)  src = Wfv + (size_t)(nn - 64) * HDIM;
        else if (nn == 96) src = Wg;
        wrow[it] = src; wnn[it] = nn; wq4[it] = kq;
    }

    // --- prologue: load tile k0=0 into registers ---
    float4 xv[8], wv[4];
#pragma unroll
    for (int q = 0; q < 8; ++q)
        xv[q] = *reinterpret_cast<const float4*>(xsrc + q * 4);
#pragma unroll
    for (int it = 0; it < 4; ++it)
        wv[it] = wrow[it]
            ? *reinterpret_cast<const float4*>(wrow[it] + wq4[it] * 4)
            : make_float4(0.f, 0.f, 0.f, 0.f);

    for (int k0 = 0; k0 < HDIM; k0 += BK) {
        lds_barrier();   // all waves done READING previous tile (lgkm only)

        // --- write staged registers to LDS ---
#pragma unroll
        for (int q = 0; q < 8; ++q) {
            Xs[q * 4 + 0][tid] = xv[q].x;
            Xs[q * 4 + 1][tid] = xv[q].y;
            Xs[q * 4 + 2][tid] = xv[q].z;
            Xs[q * 4 + 3][tid] = xv[q].w;
        }
#pragma unroll
        for (int it = 0; it < 4; ++it) {
            Ws[wq4[it] * 4 + 0][wnn[it]] = wv[it].x;
            Ws[wq4[it] * 4 + 1][wnn[it]] = wv[it].y;
            Ws[wq4[it] * 4 + 2][wnn[it]] = wv[it].z;
            Ws[wq4[it] * 4 + 3][wnn[it]] = wv[it].w;
        }

        // --- issue prefetch for next tile; stays in flight through compute ---
        const int k0n = (k0 + BK < HDIM) ? (k0 + BK) : k0;
#pragma unroll
        for (int q = 0; q < 8; ++q)
            xv[q] = *reinterpret_cast<const float4*>(xsrc + k0n + q * 4);
#pragma unroll
        for (int it = 0; it < 4; ++it)
            wv[it] = wrow[it]
                ? *reinterpret_cast<const float4*>(wrow[it] + k0n + wq4[it] * 4)
                : make_float4(0.f, 0.f, 0.f, 0.f);

        lds_barrier();   // tile visible; prefetch NOT drained

#pragma unroll 4
        for (int k = 0; k < BK; ++k) {
            float av[16], bv[8];
#pragma unroll
            for (int g = 0; g < 4; ++g) {
                const float4 a = *reinterpret_cast<const float4*>(&Xs[k][g * 64 + ty * 4]);
                av[g * 4 + 0] = a.x; av[g * 4 + 1] = a.y;
                av[g * 4 + 2] = a.z; av[g * 4 + 3] = a.w;
            }
            const float4 b0 = *reinterpret_cast<const float4*>(&Ws[k][tx * 4]);
            const float4 b1 = *reinterpret_cast<const float4*>(&Ws[k][64 + tx * 4]);
            bv[0] = b0.x; bv[1] = b0.y; bv[2] = b0.z; bv[3] = b0.w;
            bv[4] = b1.x; bv[5] = b1.y; bv[6] = b1.z; bv[7] = b1.w;
#pragma unroll
            for (int i = 0; i < 16; ++i)
#pragma unroll
                for (int j = 0; j < 8; ++j)
                    acc[i][j] = fmaf(av[i], bv[j], acc[i][j]);
        }
    }

    // --- epilogue ---
#pragma unroll
    for (int i = 0; i < 16; ++i) {
        const int rl = (i >> 2) * 64 + ty * 4 + (i & 3);
        const size_t r = (size_t)row0 + rl;
#pragma unroll
        for (int j = 0; j < 8; ++j) {
            const int c = (j < 4) ? (tx * 4 + j) : (64 + tx * 4 + (j - 4));
            const float v = acc[i][j];
            if (c < 32)        Qo [r * 32 + c]        = v + bq[c];
            else if (c < 64)   FKo[r * 32 + (c - 32)] = v + bfk[c - 32];
            else if (c < 96)   FVo[r * 32 + (c - 64)] = v + bfv[c - 64];
            else if (c == 96) {
                const float x = v + bg[0];
                G[r] = 1.f / (1.f + expf(-x));   // p_reuse
            }
        }
    }
}

// ---------------------------------------------------------------------------
// DPP cross-lane helpers: row_ror:N rotates within each 16-lane row at VALU
// latency (~8cy) instead of a ds_swizzle LDS round-trip (~120cy at 1
// wave/SIMD). 32-lane reductions = 4 DPP levels + one __shfl_xor(16).
// Rotation-reduce is exact for sum/max and exactly lexicographic for
// arg{min,max} (associative + commutative), so jnp first-index tie-break
// semantics are preserved bit-exactly.
// ---------------------------------------------------------------------------
#define DPP_ROR(n) (0x120 | (n))

template<int CTRL>
__device__ __forceinline__ float dpp_f(float x) {
    return __int_as_float(__builtin_amdgcn_update_dpp(
        0, __float_as_int(x), CTRL, 0xF, 0xF, true));
}
template<int CTRL>
__device__ __forceinline__ int dpp_i(int x) {
    return __builtin_amdgcn_update_dpp(0, x, CTRL, 0xF, 0xF, true);
}

__device__ __forceinline__ float grp_sum32(float v) {
    v += dpp_f<DPP_ROR(1)>(v);
    v += dpp_f<DPP_ROR(2)>(v);
    v += dpp_f<DPP_ROR(4)>(v);
    v += dpp_f<DPP_ROR(8)>(v);
    v += __shfl_xor(v, 16);
    return v;
}
__device__ __forceinline__ float grp_max32(float v) {
    v = fmaxf(v, dpp_f<DPP_ROR(1)>(v));
    v = fmaxf(v, dpp_f<DPP_ROR(2)>(v));
    v = fmaxf(v, dpp_f<DPP_ROR(4)>(v));
    v = fmaxf(v, dpp_f<DPP_ROR(8)>(v));
    v = fmaxf(v, __shfl_xor(v, 16));
    return v;
}
__device__ __forceinline__ void grp_argmin32(float& v, int& i) {
    float ov; int oi;
    ov = dpp_f<DPP_ROR(1)>(v); oi = dpp_i<DPP_ROR(1)>(i);
    if (ov < v || (ov == v && oi < i)) { v = ov; i = oi; }
    ov = dpp_f<DPP_ROR(2)>(v); oi = dpp_i<DPP_ROR(2)>(i);
    if (ov < v || (ov == v && oi < i)) { v = ov; i = oi; }
    ov = dpp_f<DPP_ROR(4)>(v); oi = dpp_i<DPP_ROR(4)>(i);
    if (ov < v || (ov == v && oi < i)) { v = ov; i = oi; }
    ov = dpp_f<DPP_ROR(8)>(v); oi = dpp_i<DPP_ROR(8)>(i);
    if (ov < v || (ov == v && oi < i)) { v = ov; i = oi; }
    ov = __shfl_xor(v, 16);    oi = __shfl_xor(i, 16);
    if (ov < v || (ov == v && oi < i)) { v = ov; i = oi; }
}
__device__ __forceinline__ void grp_argmax32(float& v, int& i) {
    float ov; int oi;
    ov = dpp_f<DPP_ROR(1)>(v); oi = dpp_i<DPP_ROR(1)>(i);
    if (ov > v || (ov == v && oi < i)) { v = ov; i = oi; }
    ov = dpp_f<DPP_ROR(2)>(v); oi = dpp_i<DPP_ROR(2)>(i);
    if (ov > v || (ov == v && oi < i)) { v = ov; i = oi; }
    ov = dpp_f<DPP_ROR(4)>(v); oi = dpp_i<DPP_ROR(4)>(i);
    if (ov > v || (ov == v && oi < i)) { v = ov; i = oi; }
    ov = dpp_f<DPP_ROR(8)>(v); oi = dpp_i<DPP_ROR(8)>(i);
    if (ov > v || (ov == v && oi < i)) { v = ov; i = oi; }
    ov = __shfl_xor(v, 16);    oi = __shfl_xor(i, 16);
    if (ov > v || (ov == v && oi < i)) { v = ov; i = oi; }
}

// ---------------------------------------------------------------------------
// Kernel 2: recurrence. One 32-lane half-wave per batch element.
// Block = 128 threads = 4 batch elements. Grid = 512. Zero barriers (all
// cross-lane traffic is wave-internal; LDS ops per wave are in-order).
// NEW this round:
//  * All five 32-lane reductions via DPP row_ror + single shfl_xor(16):
//    ds-swizzle count per step drops 35 -> 5.
//  * pe (pre-division softmax numerator) stored to LDS immediately after
//    expf; ssum reduction overlaps the Vt reads; 1/ssum folded into retrv.
//    argmax still computed on pe/ssum (exact reference tie semantics).
//  * dot products split into 4 parallel accumulator chains (32 -> 8 deep).
// ---------------------------------------------------------------------------
__global__ __launch_bounds__(128) void recur_kernel(
    const float* __restrict__ G,  const float* __restrict__ Qp,
    const float* __restrict__ FKp, const float* __restrict__ FVp,
    float* __restrict__ out)
{
    __shared__ float Ks[4][MEMN][33];   // Ks[el][slot][key]
    __shared__ float Vt[4][MEMN][33];   // Vt[el][val][slot]  (transposed V)
    __shared__ float qs[4][MEMN];
    __shared__ float pe_s[4][MEMN];

    const int tid = threadIdx.x;
    const int el  = tid >> 5;          // 0..3 local batch element
    const int m   = tid & 31;          // slot / lane index
    const size_t b = (size_t)blockIdx.x * 4 + el;

#pragma unroll
    for (int k = 0; k < MEMN; ++k) { Ks[el][m][k] = 0.f; Vt[el][m][k] = 0.f; }
    float Tf  = 0.f;
    float msk = 0.f;

    const float scale = 0.17677669529663687f;  // 1/sqrt(32)
    float* es_out = out;
    float* ps_out = out + (size_t)RTOT * 32;

    size_t r = b * TSTEP;
    float q  = Qp [r * 32 + m];
    float fk = FKp[r * 32 + m];
    float fv = FVp[r * 32 + m];
    float p  = G[r];

    for (int t = 0; t < TSTEP; ++t) {
        // prefetch next step (clamped at the tail; re-load is harmless)
        const size_t rn = r + ((t < TSTEP - 1) ? 1 : 0);
        const float qn  = Qp [rn * 32 + m];
        const float fkn = FKp[rn * 32 + m];
        const float fvn = FVp[rn * 32 + m];
        const float pn  = G[rn];

        // ---- register-only reductions (off critical path, overlap) ----
        const float smk = grp_sum32(msk);           // mask sum (exact: 0/1s)
        float evv = Tf + msk * 0.001f; int ei = m;  // argmin(Tf + mask*1e-3)
        grp_argmin32(evv, ei);

        // ---- logits: lg[m] = dot(K[m][:], q) * scale, masked ----
        qs[el][m] = q;
        float a0 = 0.f, a1 = 0.f, a2 = 0.f, a3 = 0.f;
#pragma unroll
        for (int k = 0; k < MEMN; k += 4) {
            a0 = fmaf(Ks[el][m][k + 0], qs[el][k + 0], a0);
            a1 = fmaf(Ks[el][m][k + 1], qs[el][k + 1], a1);
            a2 = fmaf(Ks[el][m][k + 2], qs[el][k + 2], a2);
            a3 = fmaf(Ks[el][m][k + 3], qs[el][k + 3], a3);
        }
        const float accv = (a0 + a1) + (a2 + a3);
        const float lg = accv * scale + (1.f - msk) * (-1e9f);

        // ---- softmax ----
        const float mx = grp_max32(lg);
        const float pe = expf(lg - mx);
        pe_s[el][m] = pe;                       // store early (pre-division)
        const float ssum = grp_sum32(pe);
        const float attn = pe / ssum;           // exact ref value for argmax

        float av = attn; int ai = m;            // argmax(attn), first-index
        grp_argmax32(av, ai);

        // ---- retrv[m] = (sum_k pe[k] * Vt[m][k]) / ssum ----
        float r0 = 0.f, r1 = 0.f, r2 = 0.f, r3 = 0.f;
#pragma unroll
        for (int k = 0; k < MEMN; k += 4) {
            r0 = fmaf(pe_s[el][k + 0], Vt[el][m][k + 0], r0);
            r1 = fmaf(pe_s[el][k + 1], Vt[el][m][k + 1], r1);
            r2 = fmaf(pe_s[el][k + 2], Vt[el][m][k + 2], r2);
            r3 = fmaf(pe_s[el][k + 3], Vt[el][m][k + 3], r3);
        }
        const float rv = ((r0 + r1) + (r2 + r3)) / ssum;

        const float empty = (smk == 0.f) ? 1.f : 0.f;
        const float warm  = (t < 4) ? 1.f : 0.f;
        const float gate  = p * (1.f - empty) * (1.f - warm);
        const float e_val = gate * rv + (1.f - gate) * fv;

        es_out[r * 32 + m] = e_val;
        if (m == 0) ps_out[r] = p;

        const bool wr = (gate < 0.5f) || (warm > 0.f);

        // ---- state update (wave-internal; LDS ops in-order per wave) ----
        if (wr) { Ks[el][ei][m] = fk; Vt[el][m][ei] = fv; }

        const float x = Tf * 0.85f;
        const bool bump = wr ? (m == ei) : (m == ai);
        Tf = bump ? (x + (1.f - x)) : x;
        if (wr && m == ei) msk = 1.f;

        q = qn; fk = fkn; fv = fvn; p = pn; r = rn;
    }
}

// ---------------------------------------------------------------------------
extern "C" void kernel_launch(void* const* d_in, const int* in_sizes, int n_in,
                              void* d_out, int out_size, void* d_ws, size_t ws_size,
                              hipStream_t stream) {
    const float* h   = (const float*)d_in[0];
    const float* Wg  = (const float*)d_in[1];
    const float* bg  = (const float*)d_in[2];
    const float* Wq  = (const float*)d_in[3];
    const float* bq  = (const float*)d_in[4];
    const float* Wfk = (const float*)d_in[5];
    const float* bfk = (const float*)d_in[6];
    const float* Wfv = (const float*)d_in[7];
    const float* bfv = (const float*)d_in[8];

    // workspace: G[RTOT], Q[RTOT*32], FK[RTOT*32], FV[RTOT*32]
    float* G   = (float*)d_ws;
    float* Qp  = G + RTOT;
    float* FKp = Qp + (size_t)RTOT * 32;
    float* FVp = FKp + (size_t)RTOT * 32;

    proj_kernel<<<RTOT / BM, 256, 0, stream>>>(h, Wg, bg, Wq, bq, Wfk, bfk,
                                               Wfv, bfv, G, Qp, FKp, FVp);
    recur_kernel<<<BSZ / 4, 128, 0, stream>>>(G, Qp, FKp, FVp, (float*)d_out);
}